// Round 7
// baseline (160.289 us; speedup 1.0000x reference)
//
#include <hip/hip_runtime.h>

#define LOG2E  1.44269504088896f
#define NLOG2E (-1.44269504088896f)
#define LN2    0.693147180559945f

// DPP move: returns src value permuted by ctrl (row_mask/bank_mask full, bound_ctrl=0-fill)
template <int CTRL>
__device__ __forceinline__ float dpp_mov(float x) {
    return __int_as_float(__builtin_amdgcn_update_dpp(
        0, __float_as_int(x), CTRL, 0xF, 0xF, true));
}
// quad_perm encodings: xor1=[1,0,3,2]=0xB1, xor2=[2,3,0,1]=0x4E, bcast m=m*0x55
// row_ror:4 = 0x124, row_ror:8 = 0x128 (row-local rotate; 2 steps = full row sum)

// ---------- W_h [H,D] -> W_t [D,H] (pre-scaled by `scale`) ----------
__global__ void transpose_kernel(const float* __restrict__ Wh,
                                 float* __restrict__ Wt, int Hn, int Dn,
                                 float scale) {
    __shared__ float tile[32][33];
    int tx = threadIdx.x;        // 0..31
    int ty = threadIdx.y;        // 0..7
    int i0 = blockIdx.x * 32;    // D tile origin
    int h0 = blockIdx.y * 32;    // H tile origin
#pragma unroll
    for (int k = 0; k < 4; ++k)
        tile[ty + 8 * k][tx] = scale * Wh[(size_t)(h0 + ty + 8 * k) * Dn + (i0 + tx)];
    __syncthreads();
#pragma unroll
    for (int k = 0; k < 4; ++k)
        Wt[(size_t)(i0 + ty + 8 * k) * Hn + (h0 + tx)] = tile[tx][ty + 8 * k];
}

// ---------- pass 1: per-chunk partial x·W sums (scaled domain) ----------
__global__ __launch_bounds__(256) void partial_kernel(
    const float* __restrict__ x, const float* __restrict__ Wt,
    float* __restrict__ partial, int Dn, int Hn, int Bn, int C, int L)
{
    const int gw   = blockIdx.x * 4 + (threadIdx.x >> 6);
    const int lane = threadIdx.x & 63;
    const int b = gw % Bn;           // c-major: co-resident waves share rows
    const int c = gw / Bn;
    const float* xrow = x + (size_t)b * Dn;

    float4 acc = make_float4(0.f, 0.f, 0.f, 0.f);
    const int i0 = c * L;
#pragma unroll 4
    for (int i = i0; i < i0 + L; ++i) {
        const float xv = xrow[i];
        const float4 w4 = *(const float4*)(Wt + (size_t)i * Hn + lane * 4);
        acc.x += xv * w4.x;
        acc.y += xv * w4.y;
        acc.z += xv * w4.z;
        acc.w += xv * w4.w;
    }
    *(float4*)(partial + ((size_t)b * C + c) * Hn + lane * 4) = acc;
}

// ---------- pass 2: exclusive scan over chunks (in place) ----------
__global__ __launch_bounds__(256) void scan_kernel(
    float* __restrict__ partial, int Hn, int C)
{
    const int b    = blockIdx.x * 4 + (threadIdx.x >> 6);
    const int lane = threadIdx.x & 63;
    float* base = partial + (size_t)b * C * Hn + lane * 4;
    float4 acc = make_float4(0.f, 0.f, 0.f, 0.f);
    for (int c = 0; c < C; ++c) {
        float4 cur = *(float4*)(base + (size_t)c * Hn);
        *(float4*)(base + (size_t)c * Hn) = acc;
        acc.x += cur.x; acc.y += cur.y; acc.z += cur.z; acc.w += cur.w;
    }
}

// ---------- pass 3: main NADE chunk kernel (2 batch rows/wave, DPP reduce) ----------
// Scaled domain: Wt2 = -log2e * W^T, prefix likewise, bh2 = -log2e * b_h.
// sigma_h = rcp(1 + exp2(u_h));  u += xv*w + bh2 per step.
__global__ __launch_bounds__(256) void nade_main(
    const float* __restrict__ x,      // [B,D]
    const float* __restrict__ Wt2,    // [D,H] transposed, scaled
    const float* __restrict__ prefix, // [B,C,H] exclusive prefix, scaled
    const float* __restrict__ bh,     // [H] (unscaled)
    const float* __restrict__ aw,     // [D,H]
    const float* __restrict__ ab,     // [D]
    float* __restrict__ llp,          // [B,C] partial log-likelihoods
    int Dn, int Hn, int Bn, int C, int L)
{
    const int gw   = blockIdx.x * 4 + (threadIdx.x >> 6);
    const int lane = threadIdx.x & 63;
    const int half = Bn >> 1;
    const int bp = gw % half;        // c-major mapping over b-pairs
    const int c  = gw / half;
    const int b0 = bp * 2;
    const int b1 = b0 + 1;
    const int j = lane & 3;          // this lane's i-class within a 4-batch

    float4 bh2 = *(const float4*)(bh + lane * 4);
    bh2.x *= NLOG2E; bh2.y *= NLOG2E; bh2.z *= NLOG2E; bh2.w *= NLOG2E;

    float4 ua = *(const float4*)(prefix + ((size_t)b0 * C + c) * Hn + lane * 4);
    float4 ub = *(const float4*)(prefix + ((size_t)b1 * C + c) * Hn + lane * 4);
    const float cl = (float)(c * L);
    ua.x = fmaf(cl, bh2.x, ua.x); ua.y = fmaf(cl, bh2.y, ua.y);
    ua.z = fmaf(cl, bh2.z, ua.z); ua.w = fmaf(cl, bh2.w, ua.w);
    ub.x = fmaf(cl, bh2.x, ub.x); ub.y = fmaf(cl, bh2.y, ub.y);
    ub.z = fmaf(cl, bh2.z, ub.z); ub.w = fmaf(cl, bh2.w, ub.w);

    // wave-uniform row pointers (SALU-advanced); per-lane fixed offset
    const int lo = lane * 4;
    const float* awp = aw  + (size_t)(c * L) * Hn;
    const float* wp  = Wt2 + (size_t)(c * L) * Hn;
    const float* xpa = x   + (size_t)b0 * Dn + c * L;
    const float* xpb = x   + (size_t)b1 * Dn + c * L;
    const float* abp = ab  + c * L;

    float Aa = 0.f, Ba = 0.f;        // per-class accumulators, row b0
    float Ab = 0.f, Bb = 0.f;        // row b1

#pragma unroll 2
    for (int ii = 0; ii < L; ii += 4) {
        const float xqa = xpa[ii + j];
        const float xqb = xpb[ii + j];
        const float abq = abp[ii + j];
        float pa[4], pb[4];
#pragma unroll
        for (int m = 0; m < 4; ++m) {
            // m*Hn folds into the 13-bit immediate offset (m*1024 B)
            const float4 aw4 = *(const float4*)(awp + lo + m * Hn);
            const float4 w4  = *(const float4*)(wp  + lo + m * Hn);
            // quad broadcast of lane m's x (DPP, VALU pipe)
            float xva, xvb;
            if (m == 0)      { xva = dpp_mov<0x00>(xqa); xvb = dpp_mov<0x00>(xqb); }
            else if (m == 1) { xva = dpp_mov<0x55>(xqa); xvb = dpp_mov<0x55>(xqb); }
            else if (m == 2) { xva = dpp_mov<0xAA>(xqa); xvb = dpp_mov<0xAA>(xqb); }
            else             { xva = dpp_mov<0xFF>(xqa); xvb = dpp_mov<0xFF>(xqb); }
            // ---- row b0: hidden uses state BEFORE update m
            {
                const float s0 = __builtin_amdgcn_rcpf(1.0f + __builtin_amdgcn_exp2f(ua.x));
                const float s1 = __builtin_amdgcn_rcpf(1.0f + __builtin_amdgcn_exp2f(ua.y));
                const float s2 = __builtin_amdgcn_rcpf(1.0f + __builtin_amdgcn_exp2f(ua.z));
                const float s3 = __builtin_amdgcn_rcpf(1.0f + __builtin_amdgcn_exp2f(ua.w));
                float pm = aw4.x * s0;
                pm = fmaf(aw4.y, s1, pm);
                pm = fmaf(aw4.z, s2, pm);
                pm = fmaf(aw4.w, s3, pm);
                pa[m] = pm;
                ua.x += fmaf(xva, w4.x, bh2.x);
                ua.y += fmaf(xva, w4.y, bh2.y);
                ua.z += fmaf(xva, w4.z, bh2.z);
                ua.w += fmaf(xva, w4.w, bh2.w);
            }
            // ---- row b1
            {
                const float s0 = __builtin_amdgcn_rcpf(1.0f + __builtin_amdgcn_exp2f(ub.x));
                const float s1 = __builtin_amdgcn_rcpf(1.0f + __builtin_amdgcn_exp2f(ub.y));
                const float s2 = __builtin_amdgcn_rcpf(1.0f + __builtin_amdgcn_exp2f(ub.z));
                const float s3 = __builtin_amdgcn_rcpf(1.0f + __builtin_amdgcn_exp2f(ub.w));
                float pm = aw4.x * s0;
                pm = fmaf(aw4.y, s1, pm);
                pm = fmaf(aw4.z, s2, pm);
                pm = fmaf(aw4.w, s3, pm);
                pb[m] = pm;
                ub.x += fmaf(xvb, w4.x, bh2.x);
                ub.y += fmaf(xvb, w4.y, bh2.y);
                ub.z += fmaf(xvb, w4.z, bh2.z);
                ub.w += fmaf(xvb, w4.w, bh2.w);
            }
        }
        awp += 4 * Hn;               // SALU pointer advance, once per 4-i
        wp  += 4 * Hn;

        // quad-reduce each p[m] via DPP (VALU pipe, no DS)
#pragma unroll
        for (int m = 0; m < 4; ++m) {
            pa[m] += dpp_mov<0xB1>(pa[m]);   // xor1
            pa[m] += dpp_mov<0x4E>(pa[m]);   // xor2
            pb[m] += dpp_mov<0xB1>(pb[m]);
            pb[m] += dpp_mov<0x4E>(pb[m]);
        }
        // select my class's quad-sum
        float ta0 = (lane & 1) ? pa[1] : pa[0];
        float ta1 = (lane & 1) ? pa[3] : pa[2];
        float qa  = (lane & 2) ? ta1 : ta0;
        float tb0 = (lane & 1) ? pb[1] : pb[0];
        float tb1 = (lane & 1) ? pb[3] : pb[2];
        float qb  = (lane & 2) ? tb1 : tb0;
        // row sum via rotates (class preserved: positions mod 4 invariant)
        qa += dpp_mov<0x124>(qa);            // row_ror:4
        qa += dpp_mov<0x128>(qa);            // row_ror:8
        qb += dpp_mov<0x124>(qb);
        qb += dpp_mov<0x128>(qb);
        // cross-row: only 2 DS ops per b-row per block
        qa += __shfl_xor(qa, 16, 64);
        qa += __shfl_xor(qa, 32, 64);
        qb += __shfl_xor(qb, 16, 64);
        qb += __shfl_xor(qb, 32, 64);
        // q = full 256-h dot product for i + j (replicated over 16 lanes)
        const float sa = qa + abq;
        const float sb = qb + abq;
        const float lpa = -LN2 *
            __builtin_amdgcn_logf(1.0f + __builtin_amdgcn_exp2f(-sa * LOG2E));
        const float lpb = -LN2 *
            __builtin_amdgcn_logf(1.0f + __builtin_amdgcn_exp2f(-sb * LOG2E));
        Aa = fmaf(lpa, fmaf(2.0f, xqa, -1.0f), Aa);
        Ba += xqa;
        Ab = fmaf(lpb, fmaf(2.0f, xqb, -1.0f), Ab);
        Bb += xqb;
    }

    // each class replicated 16x across the wave
#pragma unroll
    for (int off = 32; off > 0; off >>= 1) {
        Aa += __shfl_xor(Aa, off, 64);
        Ba += __shfl_xor(Ba, off, 64);
        Ab += __shfl_xor(Ab, off, 64);
        Bb += __shfl_xor(Bb, off, 64);
    }
    if (lane == 0) {
        llp[(size_t)b0 * C + c] = (Aa - Ba) * (1.0f / 16.0f) + (float)L;
        llp[(size_t)b1 * C + c] = (Ab - Bb) * (1.0f / 16.0f) + (float)L;
    }
}

// ---------- pass 4: final reduce ----------
__global__ void final_kernel(const float* __restrict__ llp,
                             float* __restrict__ out, int Bn, int C) {
    const int b = blockIdx.x * blockDim.x + threadIdx.x;
    if (b < Bn) {
        float s = 0.f;
        for (int c = 0; c < C; ++c) s += llp[(size_t)b * C + c];
        out[b] = s;
    }
}

// ---------- fallback (round-1 style, unscaled) ----------
__global__ __launch_bounds__(64) void nade_fallback(
    const float* __restrict__ x, const float* __restrict__ Wh,
    const float* __restrict__ bh, const float* __restrict__ aw,
    const float* __restrict__ ab, float* __restrict__ out, int Dn, int Hn)
{
    const int b    = blockIdx.x;
    const int lane = threadIdx.x;
    const float* xrow = x + (size_t)b * Dn;
    float ll = 0.f;
    float accl[8];
    float bhl[8];
    for (int k = 0; k < 8; ++k) { accl[k] = 0.f; bhl[k] = 0.f; }
    const int hper = Hn / 64;
    for (int k = 0; k < hper && k < 8; ++k) bhl[k] = bh[lane * hper + k];
    for (int i = 0; i < Dn; ++i) {
        float pm = 0.f;
        for (int k = 0; k < hper && k < 8; ++k) {
            const int h = lane * hper + k;
            const float sg = __builtin_amdgcn_rcpf(
                1.0f + __builtin_amdgcn_exp2f(-accl[k] * LOG2E));
            pm = fmaf(aw[(size_t)i * Hn + h], sg, pm);
        }
        for (int off = 32; off > 0; off >>= 1) pm += __shfl_xor(pm, off, 64);
        const float s = pm + ab[i];
        const float lp = -LN2 *
            __builtin_amdgcn_logf(1.0f + __builtin_amdgcn_exp2f(-s * LOG2E));
        const float xv = xrow[i];
        ll += xv * lp + (1.0f - xv) * (1.0f - lp);
        for (int k = 0; k < hper && k < 8; ++k) {
            const int h = lane * hper + k;
            accl[k] = fmaf(xv, Wh[(size_t)h * Dn + i], accl[k]) + bhl[k];
        }
    }
    if (lane == 0) out[b] = ll;
}

extern "C" void kernel_launch(void* const* d_in, const int* in_sizes, int n_in,
                              void* d_out, int out_size, void* d_ws, size_t ws_size,
                              hipStream_t stream) {
    const float* x  = (const float*)d_in[0];
    const float* Wh = (const float*)d_in[1];
    const float* bh = (const float*)d_in[2];
    const float* aw = (const float*)d_in[3];
    const float* ab = (const float*)d_in[4];
    float* out = (float*)d_out;

    const int Bn = out_size;          // 1024
    const int Hn = in_sizes[2];       // 256
    const int Dn = in_sizes[4];       // 1024
    const int C  = 8;
    const int L  = Dn / C;

    const size_t wt_bytes  = (size_t)Dn * Hn * sizeof(float);
    const size_t pf_bytes  = (size_t)Bn * C * Hn * sizeof(float);
    const size_t llp_bytes = (size_t)Bn * C * sizeof(float);

    const bool shapes_ok = (Hn == 256) && (Dn % (32 * C) == 0) && (L % 8 == 0) &&
                           (Bn % 4 == 0) && (((Bn / 2) * C) % 4 == 0);
    const bool full_path = shapes_ok && ws_size >= wt_bytes + pf_bytes + llp_bytes;

    if (full_path) {
        float* Wt2    = (float*)d_ws;
        float* prefix = (float*)((char*)d_ws + wt_bytes);
        float* llp    = (float*)((char*)d_ws + wt_bytes + pf_bytes);

        transpose_kernel<<<dim3(Dn / 32, Hn / 32), dim3(32, 8), 0, stream>>>(
            Wh, Wt2, Hn, Dn, NLOG2E);
        partial_kernel<<<(Bn * C) / 4, 256, 0, stream>>>(
            x, Wt2, prefix, Dn, Hn, Bn, C, L);
        scan_kernel<<<Bn / 4, 256, 0, stream>>>(prefix, Hn, C);
        nade_main<<<((Bn / 2) * C) / 4, 256, 0, stream>>>(
            x, Wt2, prefix, bh, aw, ab, llp, Dn, Hn, Bn, C, L);
        final_kernel<<<(Bn + 255) / 256, 256, 0, stream>>>(llp, out, Bn, C);
    } else {
        nade_fallback<<<Bn, 64, 0, stream>>>(x, Wh, bh, aw, ab, out, Dn, Hn);
    }
}

// Round 8
// 130.539 us; speedup vs baseline: 1.2279x; 1.2279x over previous
//
#include <hip/hip_runtime.h>

#define LOG2E  1.44269504088896f
#define NLOG2E (-1.44269504088896f)
#define LN2    0.693147180559945f

// DPP move: returns src value permuted by ctrl (full masks, bound_ctrl=0-fill)
template <int CTRL>
__device__ __forceinline__ float dpp_mov(float x) {
    return __int_as_float(__builtin_amdgcn_update_dpp(
        0, __float_as_int(x), CTRL, 0xF, 0xF, true));
}
// quad_perm: xor1=[1,0,3,2]=0xB1, xor2=[2,3,0,1]=0x4E; row_ror:4=0x124, row_ror:8=0x128

// ---------- W_h [H,D] -> W_t [D,H] (pre-scaled by `scale`) ----------
__global__ void transpose_kernel(const float* __restrict__ Wh,
                                 float* __restrict__ Wt, int Hn, int Dn,
                                 float scale) {
    __shared__ float tile[32][33];
    int tx = threadIdx.x;        // 0..31
    int ty = threadIdx.y;        // 0..7
    int i0 = blockIdx.x * 32;    // D tile origin
    int h0 = blockIdx.y * 32;    // H tile origin
#pragma unroll
    for (int k = 0; k < 4; ++k)
        tile[ty + 8 * k][tx] = scale * Wh[(size_t)(h0 + ty + 8 * k) * Dn + (i0 + tx)];
    __syncthreads();
#pragma unroll
    for (int k = 0; k < 4; ++k)
        Wt[(size_t)(i0 + ty + 8 * k) * Hn + (h0 + tx)] = tile[tx][ty + 8 * k];
}

// ---------- pass 1: per-chunk partial x·W sums (scaled domain) ----------
__global__ __launch_bounds__(256) void partial_kernel(
    const float* __restrict__ x, const float* __restrict__ Wt,
    float* __restrict__ partial, int Dn, int Hn, int Bn, int C, int L)
{
    const int gw   = blockIdx.x * 4 + (threadIdx.x >> 6);
    const int lane = threadIdx.x & 63;
    const int b = gw % Bn;           // c-major: co-resident waves share rows
    const int c = gw / Bn;
    const float* xrow = x + (size_t)b * Dn;

    float4 acc = make_float4(0.f, 0.f, 0.f, 0.f);
    const int i0 = c * L;
#pragma unroll 4
    for (int i = i0; i < i0 + L; ++i) {
        const float xv = xrow[i];
        const float4 w4 = *(const float4*)(Wt + (size_t)i * Hn + lane * 4);
        acc.x += xv * w4.x;
        acc.y += xv * w4.y;
        acc.z += xv * w4.z;
        acc.w += xv * w4.w;
    }
    *(float4*)(partial + ((size_t)b * C + c) * Hn + lane * 4) = acc;
}

// ---------- pass 2: exclusive scan over chunks (in place) ----------
__global__ __launch_bounds__(256) void scan_kernel(
    float* __restrict__ partial, int Hn, int C)
{
    const int b    = blockIdx.x * 4 + (threadIdx.x >> 6);
    const int lane = threadIdx.x & 63;
    float* base = partial + (size_t)b * C * Hn + lane * 4;
    float4 acc = make_float4(0.f, 0.f, 0.f, 0.f);
    for (int c = 0; c < C; ++c) {
        float4 cur = *(float4*)(base + (size_t)c * Hn);
        *(float4*)(base + (size_t)c * Hn) = acc;
        acc.x += cur.x; acc.y += cur.y; acc.z += cur.z; acc.w += cur.w;
    }
}

// ---------- pass 3: main NADE chunk kernel (batched loads, short chains) ----------
// Scaled domain: Wt2 = -log2e * W^T, prefix likewise, bh2 = -log2e * b_h.
// sigma_h = rcp(1 + exp2(u_h));  u += xv*w + bh2 per step.
__global__ __launch_bounds__(256) void nade_main(
    const float* __restrict__ x,      // [B,D]
    const float* __restrict__ Wt2,    // [D,H] transposed, scaled
    const float* __restrict__ prefix, // [B,C,H] exclusive prefix, scaled
    const float* __restrict__ bh,     // [H] (unscaled)
    const float* __restrict__ aw,     // [D,H]
    const float* __restrict__ ab,     // [D]
    float* __restrict__ llp,          // [B,C] partial log-likelihoods
    int Dn, int Hn, int Bn, int C, int L)
{
    const int gw   = blockIdx.x * 4 + (threadIdx.x >> 6);
    const int lane = threadIdx.x & 63;
    const int b = gw % Bn;           // c-major: block's 4 waves share rows+phase
    const int c = gw / Bn;
    const int j = lane & 3;          // this lane's i-class within a 4-batch

    float4 bh2 = *(const float4*)(bh + lane * 4);
    bh2.x *= NLOG2E; bh2.y *= NLOG2E; bh2.z *= NLOG2E; bh2.w *= NLOG2E;

    float4 u = *(const float4*)(prefix + ((size_t)b * C + c) * Hn + lane * 4);
    const float cl = (float)(c * L);
    u.x = fmaf(cl, bh2.x, u.x); u.y = fmaf(cl, bh2.y, u.y);
    u.z = fmaf(cl, bh2.z, u.z); u.w = fmaf(cl, bh2.w, u.w);

    const int lo = lane * 4;
    const float* awp = aw  + (size_t)(c * L) * Hn + lo;
    const float* wp  = Wt2 + (size_t)(c * L) * Hn + lo;
    const float* xp  = x   + (size_t)b * Dn + c * L;   // 16B-aligned (Dn,L mult of 4)
    const float* abp = ab  + c * L;

    float A  = 0.f;                  // sum of lp*(2*x-1) over my i-class
    float Bs = 0.f;                  // sum of x over my i-class

    for (int ii = 0; ii < L; ii += 4) {
        // ================= batch load phase (all independent, one waitcnt) ====
        const float4 a0 = *(const float4*)(awp);
        const float4 a1 = *(const float4*)(awp + Hn);
        const float4 a2 = *(const float4*)(awp + 2 * Hn);
        const float4 a3 = *(const float4*)(awp + 3 * Hn);
        const float4 w0 = *(const float4*)(wp);
        const float4 w1 = *(const float4*)(wp + Hn);
        const float4 w2 = *(const float4*)(wp + 2 * Hn);
        const float4 w3 = *(const float4*)(wp + 3 * Hn);
        const float4 x4  = *(const float4*)(xp + ii);    // wave-uniform broadcast
        const float4 ab4 = *(const float4*)(abp + ii);   // wave-uniform broadcast
        awp += 4 * Hn;
        wp  += 4 * Hn;

        // per-lane class values via static select (no DS)
        const float t0x = (j & 1) ? x4.y  : x4.x;
        const float t1x = (j & 1) ? x4.w  : x4.z;
        const float xq  = (j & 2) ? t1x   : t0x;
        const float t0a = (j & 1) ? ab4.y : ab4.x;
        const float t1a = (j & 1) ? ab4.w : ab4.z;
        const float abq = (j & 2) ? t1a   : t0a;

        // ================= compute phase ====================================
        float p0, p1, p2, p3;
        {   // m = 0 (sigmoid BEFORE update: exclusive prefix)
            const float s0 = __builtin_amdgcn_rcpf(1.0f + __builtin_amdgcn_exp2f(u.x));
            const float s1 = __builtin_amdgcn_rcpf(1.0f + __builtin_amdgcn_exp2f(u.y));
            const float s2 = __builtin_amdgcn_rcpf(1.0f + __builtin_amdgcn_exp2f(u.z));
            const float s3 = __builtin_amdgcn_rcpf(1.0f + __builtin_amdgcn_exp2f(u.w));
            p0 = fmaf(a0.w, s3, fmaf(a0.z, s2, fmaf(a0.y, s1, a0.x * s0)));
            u.x += fmaf(x4.x, w0.x, bh2.x); u.y += fmaf(x4.x, w0.y, bh2.y);
            u.z += fmaf(x4.x, w0.z, bh2.z); u.w += fmaf(x4.x, w0.w, bh2.w);
        }
        {   // m = 1
            const float s0 = __builtin_amdgcn_rcpf(1.0f + __builtin_amdgcn_exp2f(u.x));
            const float s1 = __builtin_amdgcn_rcpf(1.0f + __builtin_amdgcn_exp2f(u.y));
            const float s2 = __builtin_amdgcn_rcpf(1.0f + __builtin_amdgcn_exp2f(u.z));
            const float s3 = __builtin_amdgcn_rcpf(1.0f + __builtin_amdgcn_exp2f(u.w));
            p1 = fmaf(a1.w, s3, fmaf(a1.z, s2, fmaf(a1.y, s1, a1.x * s0)));
            u.x += fmaf(x4.y, w1.x, bh2.x); u.y += fmaf(x4.y, w1.y, bh2.y);
            u.z += fmaf(x4.y, w1.z, bh2.z); u.w += fmaf(x4.y, w1.w, bh2.w);
        }
        {   // m = 2
            const float s0 = __builtin_amdgcn_rcpf(1.0f + __builtin_amdgcn_exp2f(u.x));
            const float s1 = __builtin_amdgcn_rcpf(1.0f + __builtin_amdgcn_exp2f(u.y));
            const float s2 = __builtin_amdgcn_rcpf(1.0f + __builtin_amdgcn_exp2f(u.z));
            const float s3 = __builtin_amdgcn_rcpf(1.0f + __builtin_amdgcn_exp2f(u.w));
            p2 = fmaf(a2.w, s3, fmaf(a2.z, s2, fmaf(a2.y, s1, a2.x * s0)));
            u.x += fmaf(x4.z, w2.x, bh2.x); u.y += fmaf(x4.z, w2.y, bh2.y);
            u.z += fmaf(x4.z, w2.z, bh2.z); u.w += fmaf(x4.z, w2.w, bh2.w);
        }
        {   // m = 3
            const float s0 = __builtin_amdgcn_rcpf(1.0f + __builtin_amdgcn_exp2f(u.x));
            const float s1 = __builtin_amdgcn_rcpf(1.0f + __builtin_amdgcn_exp2f(u.y));
            const float s2 = __builtin_amdgcn_rcpf(1.0f + __builtin_amdgcn_exp2f(u.z));
            const float s3 = __builtin_amdgcn_rcpf(1.0f + __builtin_amdgcn_exp2f(u.w));
            p3 = fmaf(a3.w, s3, fmaf(a3.z, s2, fmaf(a3.y, s1, a3.x * s0)));
            u.x += fmaf(x4.w, w3.x, bh2.x); u.y += fmaf(x4.w, w3.y, bh2.y);
            u.z += fmaf(x4.w, w3.z, bh2.z); u.w += fmaf(x4.w, w3.w, bh2.w);
        }

        // ============ reduce: DPP quad + select + DPP row + 2 bpermute =======
        p0 += dpp_mov<0xB1>(p0); p0 += dpp_mov<0x4E>(p0);
        p1 += dpp_mov<0xB1>(p1); p1 += dpp_mov<0x4E>(p1);
        p2 += dpp_mov<0xB1>(p2); p2 += dpp_mov<0x4E>(p2);
        p3 += dpp_mov<0xB1>(p3); p3 += dpp_mov<0x4E>(p3);
        const float tq0 = (lane & 1) ? p1 : p0;
        const float tq1 = (lane & 1) ? p3 : p2;
        float q = (lane & 2) ? tq1 : tq0;
        q += dpp_mov<0x124>(q);          // row_ror:4  (sum quads in row)
        q += dpp_mov<0x128>(q);          // row_ror:8
        q += __shfl_xor(q, 16, 64);      // cross-row (DS, depth 2 only)
        q += __shfl_xor(q, 32, 64);
        // q = full 256-h dot for i = c*L + ii + j (replicated per class)
        const float s = q + abq;
        const float lp = -LN2 *
            __builtin_amdgcn_logf(1.0f + __builtin_amdgcn_exp2f(-s * LOG2E));
        A = fmaf(lp, fmaf(2.0f, xq, -1.0f), A);
        Bs += xq;
    }

    // each class replicated 16x across the wave
#pragma unroll
    for (int off = 32; off > 0; off >>= 1) {
        A  += __shfl_xor(A, off, 64);
        Bs += __shfl_xor(Bs, off, 64);
    }
    if (lane == 0)
        llp[(size_t)b * C + c] = (A - Bs) * (1.0f / 16.0f) + (float)L;
}

// ---------- pass 4: final reduce ----------
__global__ void final_kernel(const float* __restrict__ llp,
                             float* __restrict__ out, int Bn, int C) {
    const int b = blockIdx.x * blockDim.x + threadIdx.x;
    if (b < Bn) {
        float s = 0.f;
        for (int c = 0; c < C; ++c) s += llp[(size_t)b * C + c];
        out[b] = s;
    }
}

// ---------- fallback (round-1 style, unscaled) ----------
__global__ __launch_bounds__(64) void nade_fallback(
    const float* __restrict__ x, const float* __restrict__ Wh,
    const float* __restrict__ bh, const float* __restrict__ aw,
    const float* __restrict__ ab, float* __restrict__ out, int Dn, int Hn)
{
    const int b    = blockIdx.x;
    const int lane = threadIdx.x;
    const float* xrow = x + (size_t)b * Dn;
    float ll = 0.f;
    float accl[8];
    float bhl[8];
    for (int k = 0; k < 8; ++k) { accl[k] = 0.f; bhl[k] = 0.f; }
    const int hper = Hn / 64;
    for (int k = 0; k < hper && k < 8; ++k) bhl[k] = bh[lane * hper + k];
    for (int i = 0; i < Dn; ++i) {
        float pm = 0.f;
        for (int k = 0; k < hper && k < 8; ++k) {
            const int h = lane * hper + k;
            const float sg = __builtin_amdgcn_rcpf(
                1.0f + __builtin_amdgcn_exp2f(-accl[k] * LOG2E));
            pm = fmaf(aw[(size_t)i * Hn + h], sg, pm);
        }
        for (int off = 32; off > 0; off >>= 1) pm += __shfl_xor(pm, off, 64);
        const float s = pm + ab[i];
        const float lp = -LN2 *
            __builtin_amdgcn_logf(1.0f + __builtin_amdgcn_exp2f(-s * LOG2E));
        const float xv = xrow[i];
        ll += xv * lp + (1.0f - xv) * (1.0f - lp);
        for (int k = 0; k < hper && k < 8; ++k) {
            const int h = lane * hper + k;
            accl[k] = fmaf(xv, Wh[(size_t)h * Dn + i], accl[k]) + bhl[k];
        }
    }
    if (lane == 0) out[b] = ll;
}

extern "C" void kernel_launch(void* const* d_in, const int* in_sizes, int n_in,
                              void* d_out, int out_size, void* d_ws, size_t ws_size,
                              hipStream_t stream) {
    const float* x  = (const float*)d_in[0];
    const float* Wh = (const float*)d_in[1];
    const float* bh = (const float*)d_in[2];
    const float* aw = (const float*)d_in[3];
    const float* ab = (const float*)d_in[4];
    float* out = (float*)d_out;

    const int Bn = out_size;          // 1024
    const int Hn = in_sizes[2];       // 256
    const int Dn = in_sizes[4];       // 1024
    const int C  = 8;
    const int L  = Dn / C;

    const size_t wt_bytes  = (size_t)Dn * Hn * sizeof(float);
    const size_t pf_bytes  = (size_t)Bn * C * Hn * sizeof(float);
    const size_t llp_bytes = (size_t)Bn * C * sizeof(float);

    const bool shapes_ok = (Hn == 256) && (Dn % (32 * C) == 0) && (L % 4 == 0) &&
                           (Bn % 4 == 0);
    const bool full_path = shapes_ok && ws_size >= wt_bytes + pf_bytes + llp_bytes;

    if (full_path) {
        float* Wt2    = (float*)d_ws;
        float* prefix = (float*)((char*)d_ws + wt_bytes);
        float* llp    = (float*)((char*)d_ws + wt_bytes + pf_bytes);

        transpose_kernel<<<dim3(Dn / 32, Hn / 32), dim3(32, 8), 0, stream>>>(
            Wh, Wt2, Hn, Dn, NLOG2E);
        partial_kernel<<<(Bn * C) / 4, 256, 0, stream>>>(
            x, Wt2, prefix, Dn, Hn, Bn, C, L);
        scan_kernel<<<Bn / 4, 256, 0, stream>>>(prefix, Hn, C);
        nade_main<<<(Bn * C) / 4, 256, 0, stream>>>(
            x, Wt2, prefix, bh, aw, ab, llp, Dn, Hn, Bn, C, L);
        final_kernel<<<(Bn + 255) / 256, 256, 0, stream>>>(llp, out, Bn, C);
    } else {
        nade_fallback<<<Bn, 64, 0, stream>>>(x, Wh, bh, aw, ab, out, Dn, Hn);
    }
}